// Round 2
// baseline (130.214 us; speedup 1.0000x reference)
//
#include <hip/hip_runtime.h>
#include <hip/hip_bf16.h>
#include <math.h>

#define CHN 192
#define BATCHN 65536
#define NBLOCKS 4096
#define ROWS_PER_BLOCK (BATCHN / NBLOCKS)   // 16

#define KSCALE 2.885390081777926f   // 2*log2(e)
#define LOG2E  1.4426950408889634f

// ---- fast device math -------------------------------------------------------
__device__ __forceinline__ float fast_rcp(float x)  { return __builtin_amdgcn_rcpf(x); }
__device__ __forceinline__ float fast_exp2(float x) { return __builtin_amdgcn_exp2f(x); }

// accurate softplus for the once-per-block weight transform
__device__ __forceinline__ float softplus_acc(float h) {
    if (h > 20.0f) return h;
    return log1pf(expf(h));
}

// ---- per-channel transformed weights (all trans-derived -> stay in VGPRs) ---
// Scaled domain: v' = K*v, K = 2*log2(e). Then exp2(t') = e^(2t) and
// tanh(t) = 1 - 2*rcp(exp2(t')+1)  (sign-correct for all t, no abs needed).
struct WReg {
    // L0, unit i: q = fma(W0K, x, B0K); E = exp2(q)
    //   branch +: r = rcp(fma(E, cp, 1)); v' = fma(T2_0, r, q + gp)
    //   branch -: r = rcp(fma(E, cm, 1)); v' = fma(T2_0, r, q + gm)
    float W0K[3], B0K[3], cp[3], cm[3], gp[3], gm[3], T2_0[3];
    // L1/L2, unit p: t' = B K + sum W*v'; r = rcp(exp2(t')+1); v' = fma(T2, r, t'+T1K)
    float W1[9], B1K[3], T1K[3], T2_1[3];
    float W2[9], B2K[3], T2K[3], T2_2[3];
    // L3: s'' = b3n + sum W3n*v'   (s'' = -log2e * s);  p = rcp(exp2(s'')+1)
    float W3n[3], b3n;
};

__device__ __forceinline__ void layer3(const float* __restrict__ W,
                                       const float* __restrict__ BK,
                                       const float* __restrict__ T1K,
                                       const float* __restrict__ T2,
                                       const float in[3], float out[3]) {
#pragma unroll
    for (int p = 0; p < 3; ++p) {
        float t = BK[p];
#pragma unroll
        for (int i = 0; i < 3; ++i) t = fmaf(in[i], W[i * 3 + p], t);
        float r = fast_rcp(fast_exp2(t) + 1.0f);
        out[p] = fmaf(T2[p], r, t + T1K[p]);
    }
}

__device__ __forceinline__ float density_pair(const WReg& w, float xv) {
    // ---- layer 0 with shared exp2 across the two CDF branches ----
    float vp[3], vm[3];
#pragma unroll
    for (int i = 0; i < 3; ++i) {
        float q  = fmaf(w.W0K[i], xv, w.B0K[i]);
        float E  = fast_exp2(q);
        float rp = fast_rcp(fmaf(E, w.cp[i], 1.0f));
        float rm = fast_rcp(fmaf(E, w.cm[i], 1.0f));
        vp[i] = fmaf(w.T2_0[i], rp, q + w.gp[i]);
        vm[i] = fmaf(w.T2_0[i], rm, q + w.gm[i]);
    }
    float zp[3], zm[3];
    layer3(w.W1, w.B1K, w.T1K, w.T2_1, vp, zp);
    layer3(w.W1, w.B1K, w.T1K, w.T2_1, vm, zm);
    float yp[3], ym[3];
    layer3(w.W2, w.B2K, w.T2K, w.T2_2, zp, yp);
    layer3(w.W2, w.B2K, w.T2K, w.T2_2, zm, ym);

    float sp = w.b3n, sm = w.b3n;
#pragma unroll
    for (int i = 0; i < 3; ++i) {
        sp = fmaf(yp[i], w.W3n[i], sp);
        sm = fmaf(ym[i], w.W3n[i], sm);
    }
    float pp = fast_rcp(fast_exp2(sp) + 1.0f);
    float pm = fast_rcp(fast_exp2(sm) + 1.0f);
    return pp - pm;
}

__global__ __launch_bounds__(CHN) void density_kernel(
    const float* __restrict__ x,
    const float* __restrict__ a0, const float* __restrict__ a1, const float* __restrict__ a2,
    const float* __restrict__ b0, const float* __restrict__ b1, const float* __restrict__ b2,
    const float* __restrict__ b3,
    const float* __restrict__ H0, const float* __restrict__ H1, const float* __restrict__ H2,
    const float* __restrict__ H3,
    float* __restrict__ out)
{
    const int c = threadIdx.x;          // thread <-> channel

    // ---- once per block: transform weights (trans-derived -> register-resident)
    WReg w;
#pragma unroll
    for (int i = 0; i < 3; ++i) {
        float t0 = tanhf(a0[c * 3 + i]);
        float t1 = tanhf(a1[c * 3 + i]);
        float t2 = tanhf(a2[c * 3 + i]);
        float w0 = softplus_acc(H0[c * 3 + i]);   // H0: (C,1,3)
        float w0k = KSCALE * w0;
        w.W0K[i] = w0k;
        w.B0K[i] = KSCALE * b0[c * 3 + i];
        w.cp[i]  = exp2f( 0.5f * w0k);
        w.cm[i]  = exp2f(-0.5f * w0k);
        w.gp[i]  =  0.5f * w0k + KSCALE * t0;
        w.gm[i]  = -0.5f * w0k + KSCALE * t0;
        w.T2_0[i] = -2.0f * KSCALE * t0;

        w.B1K[i] = KSCALE * b1[c * 3 + i];
        w.T1K[i] = KSCALE * t1;
        w.T2_1[i] = -2.0f * KSCALE * t1;

        w.B2K[i] = KSCALE * b2[c * 3 + i];
        w.T2K[i] = KSCALE * t2;
        w.T2_2[i] = -2.0f * KSCALE * t2;

        w.W3n[i] = -0.5f * softplus_acc(H3[c * 3 + i]);  // -log2e/K = -1/2
    }
#pragma unroll
    for (int i = 0; i < 9; ++i) {
        w.W1[i] = softplus_acc(H1[c * 9 + i]);   // (C,3,3) row-major [i][p]
        w.W2[i] = softplus_acc(H2[c * 9 + i]);
    }
    w.b3n = -LOG2E * b3[c];

    // ---- main loop: coalesced (lane = channel), 2-row unroll for ILP ----
    const int b_start = blockIdx.x * ROWS_PER_BLOCK;
#pragma unroll 2
    for (int r = 0; r < ROWS_PER_BLOCK; ++r) {
        const int idx = (b_start + r) * CHN + c;
        out[idx] = density_pair(w, x[idx]);
    }
}

extern "C" void kernel_launch(void* const* d_in, const int* in_sizes, int n_in,
                              void* d_out, int out_size, void* d_ws, size_t ws_size,
                              hipStream_t stream) {
    const float* x  = (const float*)d_in[0];
    const float* a0 = (const float*)d_in[1];
    const float* a1 = (const float*)d_in[2];
    const float* a2 = (const float*)d_in[3];
    const float* b0 = (const float*)d_in[4];
    const float* b1 = (const float*)d_in[5];
    const float* b2 = (const float*)d_in[6];
    const float* b3 = (const float*)d_in[7];
    const float* H0 = (const float*)d_in[8];
    const float* H1 = (const float*)d_in[9];
    const float* H2 = (const float*)d_in[10];
    const float* H3 = (const float*)d_in[11];
    float* out = (float*)d_out;

    density_kernel<<<NBLOCKS, CHN, 0, stream>>>(x, a0, a1, a2, b0, b1, b2, b3,
                                                H0, H1, H2, H3, out);
}